// Round 4
// baseline (267.094 us; speedup 1.0000x reference)
//
#include <hip/hip_runtime.h>
#include <hip/hip_bf16.h>
#include <math.h>

#define EPT 8       // edges per thread in scatter kernel (8 -> 782 blocks, ~3/CU)
#define BCAP 16384  // bucket capacity (avg ~8.2k for uniform random, +90 sigma)

typedef _Float16 half8 __attribute__((ext_vector_type(8)));
typedef _Float16 half2v __attribute__((ext_vector_type(2)));
typedef float f32x4 __attribute__((ext_vector_type(4)));

__device__ __forceinline__ unsigned short f16r(float f) {
    _Float16 h = (_Float16)f;
    return __builtin_bit_cast(unsigned short, h);
}
__device__ __forceinline__ half2v h2(unsigned u) {
    return __builtin_bit_cast(half2v, u);
}

// ---------------- CSR build: single-pass 512-node bucket binning ----------------
// bucket b = dst >> 9; edge record = (src << 9) | (dst & 511)  [needs N <= 131072]
// ebuf records are written with NON-TEMPORAL stores: the scatter touches each
// 64B line ~16x from blocks on different (non-coherent) XCD L2s; nt stores
// merge at the shared memory-side IF$ instead of ping-ponging write-allocate
// lines between L2s.

__launch_bounds__(256, 8)
__global__ void scat1_kernel(const int* __restrict__ src, const int* __restrict__ dst,
                             int* __restrict__ cntg, unsigned* __restrict__ ebuf, int E) {
    __shared__ int lh[256];
    __shared__ int lbase[256];
    int tid = threadIdx.x;
    lh[tid] = 0;
    __syncthreads();
    int base = blockIdx.x * (256 * EPT);
    int ds[EPT], ss[EPT];
#pragma unroll
    for (int k = 0; k < EPT; ++k) {
        int e = base + k * 256 + tid;
        ds[k] = (e < E) ? dst[e] : -1;
        ss[k] = (e < E) ? src[e] : 0;
    }
#pragma unroll
    for (int k = 0; k < EPT; ++k) {
        if (ds[k] >= 0) atomicAdd(&lh[ds[k] >> 9], 1);
    }
    __syncthreads();
    if (lh[tid] > 0) lbase[tid] = atomicAdd(&cntg[tid], lh[tid]);
    lh[tid] = 0;
    __syncthreads();
#pragma unroll
    for (int k = 0; k < EPT; ++k) {
        if (ds[k] >= 0) {
            int b = ds[k] >> 9;
            int pos = lbase[b] + atomicAdd(&lh[b], 1);
            unsigned rec = ((unsigned)ss[k] << 9) | (unsigned)(ds[k] & 511);
            __builtin_nontemporal_store(rec, &ebuf[(size_t)b * BCAP + pos]);
        }
    }
}

__global__ void build_kernel(const unsigned* __restrict__ ebuf, const int* __restrict__ cntg,
                             int* __restrict__ row_ptr, int* __restrict__ col,
                             float* __restrict__ dinv, int N, int E) {
    __shared__ int deg[512];
    __shared__ int sh[256];
    int b = blockIdx.x;
    int tid = threadIdx.x;

    int v = cntg[tid];
    sh[tid] = v;
    __syncthreads();
    int val = v;
    for (int off = 1; off < 256; off <<= 1) {
        int add = 0;
        if (tid >= off) add = sh[tid - off];
        __syncthreads();
        val += add;
        sh[tid] = val;
        __syncthreads();
    }
    int start = (b > 0) ? sh[b - 1] : 0;
    int cnt = cntg[b];
    __syncthreads();

    int nodeBase = b << 9;
    int nn = N - nodeBase;
    if (nn > 512) nn = 512;
    if (nn < 0) nn = 0;
    const unsigned* eb = ebuf + (size_t)b * BCAP;

    deg[tid] = 0;
    deg[tid + 256] = 0;
    __syncthreads();
    for (int j = tid; j < cnt; j += 256) {
        atomicAdd(&deg[eb[j] & 511u], 1);
    }
    __syncthreads();

    int i0 = tid * 2, i1 = i0 + 1;
    int v0 = deg[i0], v1 = deg[i1];
    int tot = v0 + v1;
    sh[tid] = tot;
    __syncthreads();
    int val2 = tot;
    for (int off = 1; off < 256; off <<= 1) {
        int add = 0;
        if (tid >= off) add = sh[tid - off];
        __syncthreads();
        val2 += add;
        sh[tid] = val2;
        __syncthreads();
    }
    int excl = val2 - tot;

    if (i0 < nn) { row_ptr[nodeBase + i0] = start + excl;      dinv[nodeBase + i0] = rsqrtf((float)v0 + 1.0f); }
    if (i1 < nn) { row_ptr[nodeBase + i1] = start + excl + v0; dinv[nodeBase + i1] = rsqrtf((float)v1 + 1.0f); }
    if (b == 0 && tid == 0) row_ptr[N] = E;
    deg[i0] = start + excl;
    deg[i1] = start + excl + v0;
    __syncthreads();

    for (int j = tid; j < cnt; j += 256) {
        unsigned rec = eb[j];
        int pos = atomicAdd(&deg[rec & 511u], 1);
        col[pos] = (int)(rec >> 9);
    }
}

// ---------------- fused convert + weight pack (fp16) ----------------

__global__ void cvtpack_kernel(const float* __restrict__ x, unsigned short* __restrict__ xb,
                               int n4, int npad, const float* __restrict__ dinv,
                               const float* __restrict__ W1, const float* __restrict__ Wh,
                               const float* __restrict__ W2, unsigned short* __restrict__ wp1,
                               unsigned short* __restrict__ wph, unsigned short* __restrict__ wp2) {
    int bid = blockIdx.x;
    if (bid < 16) {
        int i = bid * 256 + threadIdx.x;   // i in [0,4096)
        int j = i & 7;
        int lane = (i >> 3) & 63;
        int hh = (i >> 9) & 1;
        int t = i >> 10;
        int k = hh * 32 + (lane >> 4) * 8 + j;
        int cc = t * 16 + (lane & 15);
        wp1[i] = f16r(W1[k * 64 + cc]);
        wph[i] = f16r(Wh[k * 64 + cc]);
        if (t < 3) wp2[i] = f16r(cc < 40 ? W2[k * 40 + cc] : 0.f);
    } else {
        if (bid == 16 && threadIdx.x < 8) {
            *(uint4*)(xb + (size_t)npad * 64 + threadIdx.x * 8) = make_uint4(0, 0, 0, 0);
        }
        int i = (bid - 16) * 256 + threadIdx.x;
        if (i < n4) {
            float dn = dinv[i >> 4];
            float4 v = *(const float4*)(x + (size_t)i * 4);
            ushort4 o;
            o.x = f16r(v.x * dn); o.y = f16r(v.y * dn);
            o.z = f16r(v.z * dn); o.w = f16r(v.w * dn);
            *(ushort4*)(xb + (size_t)i * 4) = o;
        }
    }
}

// ---------------- fused aggregate + GEMM ----------------
// One block = one 16-node MFMA tile = 4 waves, 16 lanes per node
// (4 node-groups x 2 edge-slots x 8 channel-octs). Per 16-edge batch all 8
// gather loads are issued into a statically-indexed register array before
// any accumulate (sched_barrier pins the boundary); next batch's col/idx
// prefetched under the gathers. Accumulation order unchanged (even/odd
// split) -> same absmax. LDS row stride 72 shorts: 16B-aligned, bank-spread.

__launch_bounds__(256, 8)
__global__ void fused_relu_kernel(const unsigned short* __restrict__ h,
                                  const int* __restrict__ row_ptr,
                                  const int* __restrict__ col,
                                  const float* __restrict__ dinv,
                                  const unsigned short* __restrict__ wp,
                                  const float* __restrict__ bias,
                                  unsigned short* __restrict__ out,
                                  int n, int zrow) {
    __shared__ unsigned short tile[16][72];
    if (blockIdx.x == 0 && threadIdx.x < 8) {
        *(uint4*)(out + (size_t)zrow * 64 + threadIdx.x * 8) = make_uint4(0, 0, 0, 0);
    }
    int tid = threadIdx.x;
    int w = tid >> 6;                    // wave id = t-tile id
    int lane = tid & 63;
    int g = lane >> 4;                   // node group 0..3
    int li = lane & 15;
    int sub = li >> 3;                   // edge slot 0/1
    unsigned choff = (li & 7) * 16u;     // byte offset of channel-oct in 128B row
    int nodeBase = blockIdx.x * 16;
    int row = w * 4 + g;
    int node = nodeBase + row;

    int beg = 0, deg = -1;
    float di = 0.f;
    if (node < n) {
        beg = row_ptr[node];
        deg = row_ptr[node + 1] - beg;
        di = dinv[node];
    }
    int total = deg + 1;                 // + self edge (0 for invalid node)
    int nb = (total + 15) >> 4;          // 16-edge batches for this node
    nb = max(nb, __shfl_xor(nb, 16));    // wave-uniform max over the 4 groups
    nb = max(nb, __shfl_xor(nb, 32));

    half2v a0 = (half2v)0, a1 = (half2v)0, a2 = (half2v)0, a3 = (half2v)0;
    half2v c0 = (half2v)0, c1 = (half2v)0, c2 = (half2v)0, c3 = (half2v)0;

    // batch-0 idx
    int idx;
    {
        int e0 = li;
        idx = zrow;
        if (e0 < deg) idx = col[beg + e0];
        else if (e0 == deg) idx = node;
    }
    for (int b = 0; b < nb; ++b) {
        // prefetch next batch's idx under this batch's gathers
        int nidx = zrow;
        if (b + 1 < nb) {
            int e0 = ((b + 1) << 4) + li;
            if (e0 < deg) nidx = col[beg + e0];
            else if (e0 == deg) nidx = node;
        }
        uint4 u[8];
#pragma unroll
        for (int it = 0; it < 8; ++it) {
            int s = __shfl(idx, (g << 4) + it * 2 + sub);
            u[it] = *(const uint4*)((const char*)h + (((unsigned)s << 7) + choff));
        }
        __builtin_amdgcn_sched_barrier(0);   // all 8 gathers issued before consumes
#pragma unroll
        for (int it = 0; it < 8; ++it) {
            if (it & 1) { c0 += h2(u[it].x); c1 += h2(u[it].y); c2 += h2(u[it].z); c3 += h2(u[it].w); }
            else        { a0 += h2(u[it].x); a1 += h2(u[it].y); a2 += h2(u[it].z); a3 += h2(u[it].w); }
        }
        idx = nidx;
    }
    a0 += c0; a1 += c1; a2 += c2; a3 += c3;
    // reduce the 2 edge slots (lane bit 3)
    a0 += __builtin_bit_cast(half2v, __shfl_xor(__builtin_bit_cast(int, a0), 8));
    a1 += __builtin_bit_cast(half2v, __shfl_xor(__builtin_bit_cast(int, a1), 8));
    a2 += __builtin_bit_cast(half2v, __shfl_xor(__builtin_bit_cast(int, a2), 8));
    a3 += __builtin_bit_cast(half2v, __shfl_xor(__builtin_bit_cast(int, a3), 8));

    if (sub == 0) {
        half2v dih = __builtin_bit_cast(half2v, __builtin_amdgcn_cvt_pkrtz(di, di));
        a0 *= dih; a1 *= dih; a2 *= dih; a3 *= dih;   // v_pk_mul_f16
        uint4 o;
        o.x = __builtin_bit_cast(unsigned, a0);
        o.y = __builtin_bit_cast(unsigned, a1);
        o.z = __builtin_bit_cast(unsigned, a2);
        o.w = __builtin_bit_cast(unsigned, a3);
        *(uint4*)((char*)&tile[row][0] + choff) = o;
    }
    __syncthreads();

    // GEMM phase: wave w computes output cols [w*16, w*16+16).
    int q = lane >> 4, c = lane & 15;
    half8 bf0 = *(const half8*)(wp + w * 1024 + lane * 8);
    half8 bf1 = *(const half8*)(wp + w * 1024 + 512 + lane * 8);
    float bs = bias[w * 16 + c];
    half8 fa0 = *(const half8*)&tile[c][q * 8];
    half8 fa1 = *(const half8*)&tile[c][32 + q * 8];
    f32x4 z = {0.f, 0.f, 0.f, 0.f};
    z = __builtin_amdgcn_mfma_f32_16x16x32_f16(fa0, bf0, z, 0, 0, 0);
    z = __builtin_amdgcn_mfma_f32_16x16x32_f16(fa1, bf1, z, 0, 0, 0);
#pragma unroll
    for (int r = 0; r < 4; ++r) {
        int nodeW = nodeBase + q * 4 + r;
        if (nodeW < n) {
            float dn = dinv[nodeW];
            out[(size_t)nodeW * 64 + w * 16 + c] = f16r(fmaxf(z[r] + bs, 0.f) * dn);
        }
    }
}

// Final layer: same fused agg phase; wave 0 then runs all 3 t-tiles of
// A @ W2 + b2 and the log-softmax epilogue (40 cols).

__launch_bounds__(256, 8)
__global__ void fused_lsm_kernel(const unsigned short* __restrict__ h,
                                 const int* __restrict__ row_ptr,
                                 const int* __restrict__ col,
                                 const float* __restrict__ dinv,
                                 const unsigned short* __restrict__ wp,
                                 const float* __restrict__ bias,
                                 float* __restrict__ out,
                                 int n, int zrow) {
    __shared__ unsigned short tile[16][72];
    int tid = threadIdx.x;
    int w = tid >> 6;
    int lane = tid & 63;
    int g = lane >> 4;
    int li = lane & 15;
    int sub = li >> 3;
    unsigned choff = (li & 7) * 16u;
    int nodeBase = blockIdx.x * 16;
    int row = w * 4 + g;
    int node = nodeBase + row;

    int beg = 0, deg = -1;
    float di = 0.f;
    if (node < n) {
        beg = row_ptr[node];
        deg = row_ptr[node + 1] - beg;
        di = dinv[node];
    }
    int total = deg + 1;
    int nb = (total + 15) >> 4;
    nb = max(nb, __shfl_xor(nb, 16));
    nb = max(nb, __shfl_xor(nb, 32));

    half2v a0 = (half2v)0, a1 = (half2v)0, a2 = (half2v)0, a3 = (half2v)0;
    half2v c0a = (half2v)0, c1a = (half2v)0, c2a = (half2v)0, c3a = (half2v)0;

    int idx;
    {
        int e0 = li;
        idx = zrow;
        if (e0 < deg) idx = col[beg + e0];
        else if (e0 == deg) idx = node;
    }
    for (int b = 0; b < nb; ++b) {
        int nidx = zrow;
        if (b + 1 < nb) {
            int e0 = ((b + 1) << 4) + li;
            if (e0 < deg) nidx = col[beg + e0];
            else if (e0 == deg) nidx = node;
        }
        uint4 u[8];
#pragma unroll
        for (int it = 0; it < 8; ++it) {
            int s = __shfl(idx, (g << 4) + it * 2 + sub);
            u[it] = *(const uint4*)((const char*)h + (((unsigned)s << 7) + choff));
        }
        __builtin_amdgcn_sched_barrier(0);
#pragma unroll
        for (int it = 0; it < 8; ++it) {
            if (it & 1) { c0a += h2(u[it].x); c1a += h2(u[it].y); c2a += h2(u[it].z); c3a += h2(u[it].w); }
            else        { a0 += h2(u[it].x);  a1 += h2(u[it].y);  a2 += h2(u[it].z);  a3 += h2(u[it].w); }
        }
        idx = nidx;
    }
    a0 += c0a; a1 += c1a; a2 += c2a; a3 += c3a;
    a0 += __builtin_bit_cast(half2v, __shfl_xor(__builtin_bit_cast(int, a0), 8));
    a1 += __builtin_bit_cast(half2v, __shfl_xor(__builtin_bit_cast(int, a1), 8));
    a2 += __builtin_bit_cast(half2v, __shfl_xor(__builtin_bit_cast(int, a2), 8));
    a3 += __builtin_bit_cast(half2v, __shfl_xor(__builtin_bit_cast(int, a3), 8));

    if (sub == 0) {
        half2v dih = __builtin_bit_cast(half2v, __builtin_amdgcn_cvt_pkrtz(di, di));
        a0 *= dih; a1 *= dih; a2 *= dih; a3 *= dih;
        uint4 o;
        o.x = __builtin_bit_cast(unsigned, a0);
        o.y = __builtin_bit_cast(unsigned, a1);
        o.z = __builtin_bit_cast(unsigned, a2);
        o.w = __builtin_bit_cast(unsigned, a3);
        *(uint4*)((char*)&tile[row][0] + choff) = o;
    }
    __syncthreads();
    if (w != 0) return;

    int q = lane >> 4, c = lane & 15;
    bool v2ok = (c < 8);   // col 32+c < 40

    half8 bfrag[3][2];
#pragma unroll
    for (int t = 0; t < 3; ++t)
#pragma unroll
        for (int hh = 0; hh < 2; ++hh)
            bfrag[t][hh] = *(const half8*)(wp + t * 1024 + hh * 512 + lane * 8);
    float bs[3];
    bs[0] = bias[c];
    bs[1] = bias[16 + c];
    bs[2] = v2ok ? bias[32 + c] : 0.f;

    half8 fa0 = *(const half8*)&tile[c][q * 8];
    half8 fa1 = *(const half8*)&tile[c][32 + q * 8];

    f32x4 acc[3];
#pragma unroll
    for (int t = 0; t < 3; ++t) {
        f32x4 z = {0.f, 0.f, 0.f, 0.f};
        z = __builtin_amdgcn_mfma_f32_16x16x32_f16(fa0, bfrag[t][0], z, 0, 0, 0);
        z = __builtin_amdgcn_mfma_f32_16x16x32_f16(fa1, bfrag[t][1], z, 0, 0, 0);
        acc[t] = z;
    }

#pragma unroll
    for (int r = 0; r < 4; ++r) {
        int nodeW = nodeBase + q * 4 + r;
        if (nodeW < n) {
            float v0 = acc[0][r] + bs[0];
            float v1 = acc[1][r] + bs[1];
            float v2 = v2ok ? (acc[2][r] + bs[2]) : -INFINITY;
            float m = fmaxf(fmaxf(v0, v1), v2);
#pragma unroll
            for (int off = 1; off <= 8; off <<= 1) m = fmaxf(m, __shfl_xor(m, off));
            float s = expf(v0 - m) + expf(v1 - m) + (v2ok ? expf(v2 - m) : 0.f);
#pragma unroll
            for (int off = 1; off <= 8; off <<= 1) s += __shfl_xor(s, off);
            float ls = m + logf(s);
            float* orow = out + (size_t)nodeW * 40;
            orow[c] = v0 - ls;
            orow[16 + c] = v1 - ls;
            if (v2ok) orow[32 + c] = v2 - ls;
        }
    }
}

// ---------------- launch ----------------

extern "C" void kernel_launch(void* const* d_in, const int* in_sizes, int n_in,
                              void* d_out, int out_size, void* d_ws, size_t ws_size,
                              hipStream_t stream) {
    const float* x  = (const float*)d_in[0];
    const int* ei   = (const int*)d_in[1];
    const float* W1 = (const float*)d_in[2];
    const float* b1 = (const float*)d_in[3];
    const float* Wh = (const float*)d_in[4];
    const float* bh = (const float*)d_in[5];
    const float* W2 = (const float*)d_in[6];
    const float* b2 = (const float*)d_in[7];
    float* out = (float*)d_out;

    const int N = in_sizes[0] / 64;
    const int E = in_sizes[1] / 2;
    const int nbuk = (N + 511) >> 9;         // 512-node buckets (needs N <= 131072)
    const int nTiles = (N + 15) / 16;
    const int Npad = nTiles * 16;            // zero-row index; buffers have Npad+1 rows

    const int* srcp = ei;
    const int* dstp = ei + E;

    size_t off = 0;
    auto alloc = [&](size_t bytes) {
        size_t o = off;
        off = (off + bytes + 255) & ~(size_t)255;
        return o;
    };
    char* ws = (char*)d_ws;
    int*      cntg    = (int*)(ws + alloc(256 * 4));
    int*      row_ptr = (int*)(ws + alloc((size_t)(N + 1) * 4));
    float*    dinv    = (float*)(ws + alloc((size_t)N * 4));
    int*      col     = (int*)(ws + alloc((size_t)E * 4));
    unsigned* ebuf    = (unsigned*)(ws + alloc((size_t)nbuk * BCAP * 4));
    unsigned short* wp1  = (unsigned short*)(ws + alloc(4096 * 2));
    unsigned short* wph  = (unsigned short*)(ws + alloc(4096 * 2));
    unsigned short* wp2  = (unsigned short*)(ws + alloc(3072 * 2));
    unsigned short* xb   = (unsigned short*)(ws + alloc((size_t)(Npad + 1) * 64 * 2));
    unsigned short* gA   = (unsigned short*)(ws + alloc((size_t)(Npad + 1) * 64 * 2));
    unsigned short* gB   = (unsigned short*)(ws + alloc((size_t)(Npad + 1) * 64 * 2));
    (void)ws_size;

    hipMemsetAsync(cntg, 0, 256 * 4, stream);

    const int ebGrid = (E + 256 * EPT - 1) / (256 * EPT);
    scat1_kernel<<<ebGrid, 256, 0, stream>>>(srcp, dstp, cntg, ebuf, E);
    build_kernel<<<nbuk, 256, 0, stream>>>(ebuf, cntg, row_ptr, col, dinv, N, E);

    const int n4 = N * 16;   // float4 groups (16 per 64-ch row)
    cvtpack_kernel<<<16 + (n4 + 255) / 256, 256, 0, stream>>>(x, xb, n4, Npad, dinv,
                                                              W1, Wh, W2, wp1, wph, wp2);

    // layer 1: xb -> gA     (agg + GEMM fused)
    fused_relu_kernel<<<nTiles, 256, 0, stream>>>(xb, row_ptr, col, dinv, wp1, b1, gA, N, Npad);
    // layer 2: gA -> gB
    fused_relu_kernel<<<nTiles, 256, 0, stream>>>(gA, row_ptr, col, dinv, wph, bh, gB, N, Npad);
    // layer 3: gB -> out (log-softmax, fp32)
    fused_lsm_kernel<<<nTiles, 256, 0, stream>>>(gB, row_ptr, col, dinv, wp2, b2, out, N, Npad);
}

// Round 5
// 231.566 us; speedup vs baseline: 1.1534x; 1.1534x over previous
//
#include <hip/hip_runtime.h>
#include <hip/hip_bf16.h>
#include <math.h>

#define EPT 16      // edges per thread in scatter kernel (block = 4096 edges)
#define RECCAP 6144 // max records per 256-node bucket (mean 4096, sd ~64)

typedef _Float16 half8 __attribute__((ext_vector_type(8)));
typedef _Float16 half2v __attribute__((ext_vector_type(2)));
typedef float f32x4 __attribute__((ext_vector_type(4)));

__device__ __forceinline__ unsigned short f16r(float f) {
    _Float16 h = (_Float16)f;
    return __builtin_bit_cast(unsigned short, h);
}
__device__ __forceinline__ half2v h2(unsigned u) {
    return __builtin_bit_cast(half2v, u);
}

// ---------------- CSR build: block-local bucket sort ----------------
// bucket b = dst >> 8 (256-node buckets, nbuk = ceil(N/256) <= 510).
// Each scat1 block sorts its own 4096 edges by bucket into its OWN contiguous
// ebuf region (no cross-block write sharing, no global atomics, no memset)
// and publishes per-(bucket,block) counts/starts: ctbl/stbl[b*nblk + k].
// record = (src << 8) | (dst & 255)   [src < 2^24]

__global__ void scat1_kernel(const int* __restrict__ src, const int* __restrict__ dst,
                             unsigned* __restrict__ ebuf, int* __restrict__ ctbl,
                             int* __restrict__ stbl, int E, int nblk, int nbuk) {
    __shared__ int hist[512];
    __shared__ int shs[256];
    int tid = threadIdx.x;
    hist[tid] = 0;
    hist[tid + 256] = 0;
    __syncthreads();
    int base = blockIdx.x * (256 * EPT);
    int ds[EPT], ss[EPT];
#pragma unroll
    for (int k = 0; k < EPT; ++k) {
        int e = base + k * 256 + tid;
        ds[k] = (e < E) ? dst[e] : -1;
        ss[k] = (e < E) ? src[e] : 0;
    }
#pragma unroll
    for (int k = 0; k < EPT; ++k) {
        if (ds[k] >= 0) atomicAdd(&hist[ds[k] >> 8], 1);
    }
    __syncthreads();
    // exclusive scan over hist[512], 2 entries per thread
    int i0 = tid * 2, i1 = i0 + 1;
    int v0 = hist[i0], v1 = hist[i1];
    int tot = v0 + v1;
    shs[tid] = tot;
    __syncthreads();
    int val = tot;
    for (int off = 1; off < 256; off <<= 1) {
        int add = 0;
        if (tid >= off) add = shs[tid - off];
        __syncthreads();
        val += add;
        shs[tid] = val;
        __syncthreads();
    }
    int excl = val - tot;
    // publish per-(bucket,block) tables, layout [bucket][block] for coalesced reads
    if (i0 < nbuk) { ctbl[i0 * nblk + blockIdx.x] = v0; stbl[i0 * nblk + blockIdx.x] = excl; }
    if (i1 < nbuk) { ctbl[i1 * nblk + blockIdx.x] = v1; stbl[i1 * nblk + blockIdx.x] = excl + v0; }
    // repurpose hist as write cursors
    hist[i0] = excl;
    hist[i1] = excl + v0;
    __syncthreads();
#pragma unroll
    for (int k = 0; k < EPT; ++k) {
        if (ds[k] >= 0) {
            int pos = atomicAdd(&hist[ds[k] >> 8], 1);
            ebuf[(size_t)base + pos] = ((unsigned)ss[k] << 8) | (unsigned)(ds[k] & 255);
        }
    }
}

// blocks [0,16): pack W1/Wh/W2 into MFMA B-fragment order (+ zero xb zero-row).
// blocks [16, 16+nbuk): cntg[b] = sum_k ctbl[b][k]  (coalesced row sum).

__global__ void totals_pack_kernel(const int* __restrict__ ctbl, int* __restrict__ cntg,
                                   const float* __restrict__ W1, const float* __restrict__ Wh,
                                   const float* __restrict__ W2, unsigned short* __restrict__ wp1,
                                   unsigned short* __restrict__ wph, unsigned short* __restrict__ wp2,
                                   unsigned short* __restrict__ xb, int zrow, int nblk, int nbuk) {
    __shared__ int shs[256];
    int bid = blockIdx.x;
    int tid = threadIdx.x;
    if (bid < 16) {
        int i = bid * 256 + tid;           // i in [0,4096)
        int j = i & 7;
        int lane = (i >> 3) & 63;
        int hh = (i >> 9) & 1;
        int t = i >> 10;
        int k = hh * 32 + (lane >> 4) * 8 + j;
        int cc = t * 16 + (lane & 15);
        wp1[i] = f16r(W1[k * 64 + cc]);
        wph[i] = f16r(Wh[k * 64 + cc]);
        if (t < 3) wp2[i] = f16r(cc < 40 ? W2[k * 40 + cc] : 0.f);
        if (bid == 0 && tid < 8) {
            *(uint4*)(xb + (size_t)zrow * 64 + tid * 8) = make_uint4(0, 0, 0, 0);
        }
    } else {
        int b = bid - 16;
        int s = 0;
        for (int k = tid; k < nblk; k += 256) s += ctbl[b * nblk + k];
        shs[tid] = s;
        __syncthreads();
        for (int off = 128; off >= 1; off >>= 1) {
            if (tid < off) shs[tid] += shs[tid + off];
            __syncthreads();
        }
        if (tid == 0) cntg[b] = shs[0];
    }
}

// one block per 256-node bucket: front-scan of bucket totals -> start; gather
// this bucket's chunks from all scat1 block-regions ONCE into LDS; histogram
// -> local scan -> row_ptr/dinv -> scatter col (block-private region).
// Also converts this bucket's x rows to pre-scaled f16 (absorbs cvtpack).

__global__ void build_kernel(const unsigned* __restrict__ ebuf, const int* __restrict__ ctbl,
                             const int* __restrict__ stbl, const int* __restrict__ cntg,
                             int* __restrict__ row_ptr, int* __restrict__ col,
                             float* __restrict__ dinv, const float* __restrict__ x,
                             unsigned short* __restrict__ xb, int N, int E, int nblk, int nbuk) {
    __shared__ int shs[256];
    __shared__ int deg2[256];
    __shared__ float dl[256];
    __shared__ int s_start;
    __shared__ unsigned recs[RECCAP];
    int b = blockIdx.x;
    int tid = threadIdx.x;
    deg2[tid] = 0;

    // front: exclusive prefix over cntg[0..nbuk) -> start of this bucket
    int i0 = tid * 2, i1 = i0 + 1;
    int c0 = (i0 < nbuk) ? cntg[i0] : 0;
    int c1 = (i1 < nbuk) ? cntg[i1] : 0;
    int tot = c0 + c1;
    shs[tid] = tot;
    __syncthreads();
    int val = tot;
    for (int off = 1; off < 256; off <<= 1) {
        int add = 0;
        if (tid >= off) add = shs[tid - off];
        __syncthreads();
        val += add;
        shs[tid] = val;
        __syncthreads();
    }
    int excl = val - tot;
    if (i0 == b) s_start = excl;
    if (i1 == b) s_start = excl + c0;
    __syncthreads();
    int start = s_start;

    // gather chunks into LDS (single pass over records)
    int carry = 0;
    for (int r = 0; r * 256 < nblk; ++r) {
        int k = r * 256 + tid;
        int ck = 0, sk = 0;
        if (k < nblk) { ck = ctbl[b * nblk + k]; sk = stbl[b * nblk + k]; }
        __syncthreads();                   // protect shs/carry from prev round
        shs[tid] = ck;
        __syncthreads();
        int v = ck;
        for (int off = 1; off < 256; off <<= 1) {
            int add = 0;
            if (tid >= off) add = shs[tid - off];
            __syncthreads();
            v += add;
            shs[tid] = v;
            __syncthreads();
        }
        int ofs = carry + v - ck;
        const unsigned* eb = ebuf + (size_t)k * (256 * EPT) + sk;
#pragma unroll 4
        for (int j = 0; j < ck; ++j) {
            if (ofs + j < RECCAP) recs[ofs + j] = eb[j];
        }
        carry += shs[255];
    }
    __syncthreads();
    int cnt = carry;
    if (cnt > RECCAP) cnt = RECCAP;        // safety (statistically impossible)

    // local degree histogram
    for (int j = tid; j < cnt; j += 256) {
        atomicAdd(&deg2[recs[j] & 255u], 1);
    }
    __syncthreads();
    // scan 256 degrees (1 per thread)
    int dv = deg2[tid];
    shs[tid] = dv;
    __syncthreads();
    int v2 = dv;
    for (int off = 1; off < 256; off <<= 1) {
        int add = 0;
        if (tid >= off) add = shs[tid - off];
        __syncthreads();
        v2 += add;
        shs[tid] = v2;
        __syncthreads();
    }
    int ex2 = v2 - dv;
    int nodeBase = b << 8;
    int node = nodeBase + tid;
    float df = rsqrtf((float)dv + 1.0f);
    if (node < N) {
        row_ptr[node] = start + ex2;
        dinv[node] = df;
    }
    dl[tid] = df;
    deg2[tid] = start + ex2;               // absolute write cursor
    __syncthreads();
    if (b == 0 && tid == 0) row_ptr[N] = E;

    // scatter col (block-private contiguous region)
    for (int j = tid; j < cnt; j += 256) {
        unsigned rec = recs[j];
        int pos = atomicAdd(&deg2[rec & 255u], 1);
        col[pos] = (int)(rec >> 8);
    }

    // fused x -> f16 convert for this bucket's nodes: xb[row] = dinv[row]*x[row]
    for (int g = tid; g < 4096; g += 256) {
        int rr = g >> 4;
        int node2 = nodeBase + rr;
        if (node2 < N) {
            float dn = dl[rr];
            float4 vv = ((const float4*)x)[(size_t)node2 * 16 + (g & 15)];
            ushort4 o;
            o.x = f16r(vv.x * dn); o.y = f16r(vv.y * dn);
            o.z = f16r(vv.z * dn); o.w = f16r(vv.w * dn);
            ((ushort4*)xb)[(size_t)node2 * 16 + (g & 15)] = o;
        }
    }
}

// ---------------- fused aggregate + GEMM ----------------
// One block = one 16-node MFMA tile = 4 waves, 16 lanes per node
// (4 node-groups x 2 edge-slots x 8 channel-octs). Per 16-edge batch all 8
// gather loads are issued into a statically-indexed register array before
// any accumulate (sched_barrier pins the boundary); next batch's col/idx
// prefetched under the gathers. LDS row stride 72 shorts: 16B-aligned.

__launch_bounds__(256, 8)
__global__ void fused_relu_kernel(const unsigned short* __restrict__ h,
                                  const int* __restrict__ row_ptr,
                                  const int* __restrict__ col,
                                  const float* __restrict__ dinv,
                                  const unsigned short* __restrict__ wp,
                                  const float* __restrict__ bias,
                                  unsigned short* __restrict__ out,
                                  int n, int zrow) {
    __shared__ unsigned short tile[16][72];
    if (blockIdx.x == 0 && threadIdx.x < 8) {
        *(uint4*)(out + (size_t)zrow * 64 + threadIdx.x * 8) = make_uint4(0, 0, 0, 0);
    }
    int tid = threadIdx.x;
    int w = tid >> 6;                    // wave id = t-tile id
    int lane = tid & 63;
    int g = lane >> 4;                   // node group 0..3
    int li = lane & 15;
    int sub = li >> 3;                   // edge slot 0/1
    unsigned choff = (li & 7) * 16u;     // byte offset of channel-oct in 128B row
    int nodeBase = blockIdx.x * 16;
    int row = w * 4 + g;
    int node = nodeBase + row;

    int beg = 0, deg = -1;
    float di = 0.f;
    if (node < n) {
        beg = row_ptr[node];
        deg = row_ptr[node + 1] - beg;
        di = dinv[node];
    }
    int total = deg + 1;                 // + self edge (0 for invalid node)
    int nb = (total + 15) >> 4;          // 16-edge batches for this node
    nb = max(nb, __shfl_xor(nb, 16));    // wave-uniform max over the 4 groups
    nb = max(nb, __shfl_xor(nb, 32));

    half2v a0 = (half2v)0, a1 = (half2v)0, a2 = (half2v)0, a3 = (half2v)0;
    half2v c0 = (half2v)0, c1 = (half2v)0, c2 = (half2v)0, c3 = (half2v)0;

    // batch-0 idx
    int idx;
    {
        int e0 = li;
        idx = zrow;
        if (e0 < deg) idx = col[beg + e0];
        else if (e0 == deg) idx = node;
    }
    for (int b = 0; b < nb; ++b) {
        // prefetch next batch's idx under this batch's gathers
        int nidx = zrow;
        if (b + 1 < nb) {
            int e0 = ((b + 1) << 4) + li;
            if (e0 < deg) nidx = col[beg + e0];
            else if (e0 == deg) nidx = node;
        }
        uint4 u[8];
#pragma unroll
        for (int it = 0; it < 8; ++it) {
            int s = __shfl(idx, (g << 4) + it * 2 + sub);
            u[it] = *(const uint4*)((const char*)h + (((unsigned)s << 7) + choff));
        }
        __builtin_amdgcn_sched_barrier(0);   // all 8 gathers issued before consumes
#pragma unroll
        for (int it = 0; it < 8; ++it) {
            if (it & 1) { c0 += h2(u[it].x); c1 += h2(u[it].y); c2 += h2(u[it].z); c3 += h2(u[it].w); }
            else        { a0 += h2(u[it].x); a1 += h2(u[it].y); a2 += h2(u[it].z); a3 += h2(u[it].w); }
        }
        idx = nidx;
    }
    a0 += c0; a1 += c1; a2 += c2; a3 += c3;
    // reduce the 2 edge slots (lane bit 3)
    a0 += __builtin_bit_cast(half2v, __shfl_xor(__builtin_bit_cast(int, a0), 8));
    a1 += __builtin_bit_cast(half2v, __shfl_xor(__builtin_bit_cast(int, a1), 8));
    a2 += __builtin_bit_cast(half2v, __shfl_xor(__builtin_bit_cast(int, a2), 8));
    a3 += __builtin_bit_cast(half2v, __shfl_xor(__builtin_bit_cast(int, a3), 8));

    if (sub == 0) {
        half2v dih = __builtin_bit_cast(half2v, __builtin_amdgcn_cvt_pkrtz(di, di));
        a0 *= dih; a1 *= dih; a2 *= dih; a3 *= dih;   // v_pk_mul_f16
        uint4 o;
        o.x = __builtin_bit_cast(unsigned, a0);
        o.y = __builtin_bit_cast(unsigned, a1);
        o.z = __builtin_bit_cast(unsigned, a2);
        o.w = __builtin_bit_cast(unsigned, a3);
        *(uint4*)((char*)&tile[row][0] + choff) = o;
    }
    __syncthreads();

    // GEMM phase: wave w computes output cols [w*16, w*16+16).
    int q = lane >> 4, c = lane & 15;
    half8 bf0 = *(const half8*)(wp + w * 1024 + lane * 8);
    half8 bf1 = *(const half8*)(wp + w * 1024 + 512 + lane * 8);
    float bs = bias[w * 16 + c];
    half8 fa0 = *(const half8*)&tile[c][q * 8];
    half8 fa1 = *(const half8*)&tile[c][32 + q * 8];
    f32x4 z = {0.f, 0.f, 0.f, 0.f};
    z = __builtin_amdgcn_mfma_f32_16x16x32_f16(fa0, bf0, z, 0, 0, 0);
    z = __builtin_amdgcn_mfma_f32_16x16x32_f16(fa1, bf1, z, 0, 0, 0);
#pragma unroll
    for (int r = 0; r < 4; ++r) {
        int nodeW = nodeBase + q * 4 + r;
        if (nodeW < n) {
            float dn = dinv[nodeW];
            out[(size_t)nodeW * 64 + w * 16 + c] = f16r(fmaxf(z[r] + bs, 0.f) * dn);
        }
    }
}

// Final layer: same fused agg phase; wave 0 then runs all 3 t-tiles of
// A @ W2 + b2 and the log-softmax epilogue (40 cols).

__launch_bounds__(256, 8)
__global__ void fused_lsm_kernel(const unsigned short* __restrict__ h,
                                 const int* __restrict__ row_ptr,
                                 const int* __restrict__ col,
                                 const float* __restrict__ dinv,
                                 const unsigned short* __restrict__ wp,
                                 const float* __restrict__ bias,
                                 float* __restrict__ out,
                                 int n, int zrow) {
    __shared__ unsigned short tile[16][72];
    int tid = threadIdx.x;
    int w = tid >> 6;
    int lane = tid & 63;
    int g = lane >> 4;
    int li = lane & 15;
    int sub = li >> 3;
    unsigned choff = (li & 7) * 16u;
    int nodeBase = blockIdx.x * 16;
    int row = w * 4 + g;
    int node = nodeBase + row;

    int beg = 0, deg = -1;
    float di = 0.f;
    if (node < n) {
        beg = row_ptr[node];
        deg = row_ptr[node + 1] - beg;
        di = dinv[node];
    }
    int total = deg + 1;
    int nb = (total + 15) >> 4;
    nb = max(nb, __shfl_xor(nb, 16));
    nb = max(nb, __shfl_xor(nb, 32));

    half2v a0 = (half2v)0, a1 = (half2v)0, a2 = (half2v)0, a3 = (half2v)0;
    half2v c0a = (half2v)0, c1a = (half2v)0, c2a = (half2v)0, c3a = (half2v)0;

    int idx;
    {
        int e0 = li;
        idx = zrow;
        if (e0 < deg) idx = col[beg + e0];
        else if (e0 == deg) idx = node;
    }
    for (int b = 0; b < nb; ++b) {
        int nidx = zrow;
        if (b + 1 < nb) {
            int e0 = ((b + 1) << 4) + li;
            if (e0 < deg) nidx = col[beg + e0];
            else if (e0 == deg) nidx = node;
        }
        uint4 u[8];
#pragma unroll
        for (int it = 0; it < 8; ++it) {
            int s = __shfl(idx, (g << 4) + it * 2 + sub);
            u[it] = *(const uint4*)((const char*)h + (((unsigned)s << 7) + choff));
        }
        __builtin_amdgcn_sched_barrier(0);
#pragma unroll
        for (int it = 0; it < 8; ++it) {
            if (it & 1) { c0a += h2(u[it].x); c1a += h2(u[it].y); c2a += h2(u[it].z); c3a += h2(u[it].w); }
            else        { a0 += h2(u[it].x);  a1 += h2(u[it].y);  a2 += h2(u[it].z);  a3 += h2(u[it].w); }
        }
        idx = nidx;
    }
    a0 += c0a; a1 += c1a; a2 += c2a; a3 += c3a;
    a0 += __builtin_bit_cast(half2v, __shfl_xor(__builtin_bit_cast(int, a0), 8));
    a1 += __builtin_bit_cast(half2v, __shfl_xor(__builtin_bit_cast(int, a1), 8));
    a2 += __builtin_bit_cast(half2v, __shfl_xor(__builtin_bit_cast(int, a2), 8));
    a3 += __builtin_bit_cast(half2v, __shfl_xor(__builtin_bit_cast(int, a3), 8));

    if (sub == 0) {
        half2v dih = __builtin_bit_cast(half2v, __builtin_amdgcn_cvt_pkrtz(di, di));
        a0 *= dih; a1 *= dih; a2 *= dih; a3 *= dih;
        uint4 o;
        o.x = __builtin_bit_cast(unsigned, a0);
        o.y = __builtin_bit_cast(unsigned, a1);
        o.z = __builtin_bit_cast(unsigned, a2);
        o.w = __builtin_bit_cast(unsigned, a3);
        *(uint4*)((char*)&tile[row][0] + choff) = o;
    }
    __syncthreads();
    if (w != 0) return;

    int q = lane >> 4, c = lane & 15;
    bool v2ok = (c < 8);   // col 32+c < 40

    half8 bfrag[3][2];
#pragma unroll
    for (int t = 0; t < 3; ++t)
#pragma unroll
        for (int hh = 0; hh < 2; ++hh)
            bfrag[t][hh] = *(const half8*)(wp + t * 1024 + hh * 512 + lane * 8);
    float bs[3];
    bs[0] = bias[c];
    bs[1] = bias[16 + c];
    bs[2] = v2ok ? bias[32 + c] : 0.f;

    half8 fa0 = *(const half8*)&tile[c][q * 8];
    half8 fa1 = *(const half8*)&tile[c][32 + q * 8];

    f32x4 acc[3];
#pragma unroll
    for (int t = 0; t < 3; ++t) {
        f32x4 z = {0.f, 0.f, 0.f, 0.f};
        z = __builtin_amdgcn_mfma_f32_16x16x32_f16(fa0, bfrag[t][0], z, 0, 0, 0);
        z = __builtin_amdgcn_mfma_f32_16x16x32_f16(fa1, bfrag[t][1], z, 0, 0, 0);
        acc[t] = z;
    }

#pragma unroll
    for (int r = 0; r < 4; ++r) {
        int nodeW = nodeBase + q * 4 + r;
        if (nodeW < n) {
            float v0 = acc[0][r] + bs[0];
            float v1 = acc[1][r] + bs[1];
            float v2 = v2ok ? (acc[2][r] + bs[2]) : -INFINITY;
            float m = fmaxf(fmaxf(v0, v1), v2);
#pragma unroll
            for (int off = 1; off <= 8; off <<= 1) m = fmaxf(m, __shfl_xor(m, off));
            float s = expf(v0 - m) + expf(v1 - m) + (v2ok ? expf(v2 - m) : 0.f);
#pragma unroll
            for (int off = 1; off <= 8; off <<= 1) s += __shfl_xor(s, off);
            float ls = m + logf(s);
            float* orow = out + (size_t)nodeW * 40;
            orow[c] = v0 - ls;
            orow[16 + c] = v1 - ls;
            if (v2ok) orow[32 + c] = v2 - ls;
        }
    }
}

// ---------------- launch ----------------

extern "C" void kernel_launch(void* const* d_in, const int* in_sizes, int n_in,
                              void* d_out, int out_size, void* d_ws, size_t ws_size,
                              hipStream_t stream) {
    const float* x  = (const float*)d_in[0];
    const int* ei   = (const int*)d_in[1];
    const float* W1 = (const float*)d_in[2];
    const float* b1 = (const float*)d_in[3];
    const float* Wh = (const float*)d_in[4];
    const float* bh = (const float*)d_in[5];
    const float* W2 = (const float*)d_in[6];
    const float* b2 = (const float*)d_in[7];
    float* out = (float*)d_out;

    const int N = in_sizes[0] / 64;
    const int E = in_sizes[1] / 2;
    const int nblk = (E + 256 * EPT - 1) / (256 * EPT);  // scat1 blocks (391)
    const int nbuk = (N + 255) >> 8;                     // 256-node buckets (391, <=510)
    const int nTiles = (N + 15) / 16;
    const int Npad = nTiles * 16;                        // zero-row index

    const int* srcp = ei;
    const int* dstp = ei + E;

    size_t off = 0;
    auto alloc = [&](size_t bytes) {
        size_t o = off;
        off = (off + bytes + 255) & ~(size_t)255;
        return o;
    };
    char* ws = (char*)d_ws;
    int*      cntg    = (int*)(ws + alloc((size_t)nbuk * 4));
    int*      row_ptr = (int*)(ws + alloc((size_t)(N + 1) * 4));
    float*    dinv    = (float*)(ws + alloc((size_t)N * 4));
    int*      col     = (int*)(ws + alloc((size_t)E * 4));
    unsigned* ebuf    = (unsigned*)(ws + alloc((size_t)nblk * (256 * EPT) * 4));
    int*      ctbl    = (int*)(ws + alloc((size_t)nbuk * nblk * 4));
    int*      stbl    = (int*)(ws + alloc((size_t)nbuk * nblk * 4));
    unsigned short* wp1  = (unsigned short*)(ws + alloc(4096 * 2));
    unsigned short* wph  = (unsigned short*)(ws + alloc(4096 * 2));
    unsigned short* wp2  = (unsigned short*)(ws + alloc(3072 * 2));
    unsigned short* xb   = (unsigned short*)(ws + alloc((size_t)(Npad + 1) * 64 * 2));
    unsigned short* gA   = (unsigned short*)(ws + alloc((size_t)(Npad + 1) * 64 * 2));
    unsigned short* gB   = (unsigned short*)(ws + alloc((size_t)(Npad + 1) * 64 * 2));
    (void)ws_size;

    // CSR build (no memset needed: all tables fully overwritten)
    scat1_kernel<<<nblk, 256, 0, stream>>>(srcp, dstp, ebuf, ctbl, stbl, E, nblk, nbuk);
    totals_pack_kernel<<<16 + nbuk, 256, 0, stream>>>(ctbl, cntg, W1, Wh, W2,
                                                      wp1, wph, wp2, xb, Npad, nblk, nbuk);
    build_kernel<<<nbuk, 256, 0, stream>>>(ebuf, ctbl, stbl, cntg, row_ptr, col, dinv,
                                           x, xb, N, E, nblk, nbuk);

    const int gemmGrid = nTiles;
    // layer 1: xb -> gA     (agg + GEMM fused)
    fused_relu_kernel<<<gemmGrid, 256, 0, stream>>>(xb, row_ptr, col, dinv, wp1, b1, gA, N, Npad);
    // layer 2: gA -> gB
    fused_relu_kernel<<<gemmGrid, 256, 0, stream>>>(gA, row_ptr, col, dinv, wph, bh, gB, N, Npad);
    // layer 3: gB -> out (log-softmax, fp32)
    fused_lsm_kernel<<<gemmGrid, 256, 0, stream>>>(gB, row_ptr, col, dinv, wp2, b2, out, N, Npad);
}

// Round 6
// 226.807 us; speedup vs baseline: 1.1776x; 1.0210x over previous
//
#include <hip/hip_runtime.h>
#include <hip/hip_bf16.h>
#include <math.h>

#define EPT 16       // edges per thread in scatter kernel (block = 4096 edges)
#define BUK 128      // nodes per bucket
#define BCAP 2560    // records per bucket region (mean 2048, sd ~45 -> +11 sigma)
#define NBUKMAX 1024 // supports N <= 131072

typedef _Float16 half8 __attribute__((ext_vector_type(8)));
typedef _Float16 half2v __attribute__((ext_vector_type(2)));
typedef float f32x4 __attribute__((ext_vector_type(4)));

__device__ __forceinline__ unsigned short f16r(float f) {
    _Float16 h = (_Float16)f;
    return __builtin_bit_cast(unsigned short, h);
}
__device__ __forceinline__ half2v h2(unsigned u) {
    return __builtin_bit_cast(half2v, u);
}

// ---------------- CSR build, stage 1: LDS bucket sort + run publish --------
// bucket b = dst >> 7. Each block sorts its 4096 edges by bucket in LDS, then
// reserves space in bucket b's FINAL region with ONE global atomic per
// (block,bucket) and copies the run out. Records land bucket-contiguous in
// ebuf -- no transpose pass, no chunk tables. record = (src<<7)|(dst&127).
// Blocks [nblk, nblk+16) instead pack W1/Wh/W2 into MFMA B-fragment order.

__global__ void scat1_pack_kernel(const int* __restrict__ src, const int* __restrict__ dst,
                                  int* __restrict__ cur, unsigned* __restrict__ ebuf,
                                  const float* __restrict__ W1, const float* __restrict__ Wh,
                                  const float* __restrict__ W2, unsigned short* __restrict__ wp1,
                                  unsigned short* __restrict__ wph, unsigned short* __restrict__ wp2,
                                  unsigned short* __restrict__ xb, int zrow,
                                  int E, int nblk, int nbuk) {
    int tid = threadIdx.x;
    if ((int)blockIdx.x >= nblk) {
        // ---- weight pack (16 blocks) ----
        int bid = blockIdx.x - nblk;
        int i = bid * 256 + tid;           // i in [0,4096)
        int j = i & 7;
        int lane = (i >> 3) & 63;
        int hh = (i >> 9) & 1;
        int t = i >> 10;
        int k = hh * 32 + (lane >> 4) * 8 + j;
        int cc = t * 16 + (lane & 15);
        wp1[i] = f16r(W1[k * 64 + cc]);
        wph[i] = f16r(Wh[k * 64 + cc]);
        if (t < 3) wp2[i] = f16r(cc < 40 ? W2[k * 40 + cc] : 0.f);
        if (bid == 0 && tid < 8) {
            *(uint4*)(xb + (size_t)zrow * 64 + tid * 8) = make_uint4(0, 0, 0, 0);
        }
        return;
    }

    __shared__ int hcnt[NBUKMAX];
    __shared__ int hofs[NBUKMAX];
    __shared__ int hcur[NBUKMAX];
    __shared__ unsigned lrec[256 * EPT];
    __shared__ int shs[256];

    for (int k = tid; k < nbuk; k += 256) hcnt[k] = 0;
    __syncthreads();

    int base = blockIdx.x * (256 * EPT);
    int ds[EPT], ss[EPT];
#pragma unroll
    for (int k = 0; k < EPT; ++k) {
        int e = base + k * 256 + tid;
        ds[k] = (e < E) ? dst[e] : -1;
        ss[k] = (e < E) ? src[e] : 0;
    }
#pragma unroll
    for (int k = 0; k < EPT; ++k) {
        if (ds[k] >= 0) atomicAdd(&hcnt[ds[k] >> 7], 1);
    }
    __syncthreads();

    // exclusive scan over hcnt[nbuk], 4 entries per thread
    int k0 = tid * 4;
    int s = 0;
#pragma unroll
    for (int q = 0; q < 4; ++q) {
        int k = k0 + q;
        if (k < nbuk) s += hcnt[k];
    }
    shs[tid] = s;
    __syncthreads();
    int val = s;
    for (int off = 1; off < 256; off <<= 1) {
        int add = 0;
        if (tid >= off) add = shs[tid - off];
        __syncthreads();
        val += add;
        shs[tid] = val;
        __syncthreads();
    }
    int run = val - s;
#pragma unroll
    for (int q = 0; q < 4; ++q) {
        int k = k0 + q;
        if (k < nbuk) { hofs[k] = run; hcur[k] = run; run += hcnt[k]; }
    }
    __syncthreads();

    // scatter records into LDS, sorted by bucket
#pragma unroll
    for (int k = 0; k < EPT; ++k) {
        if (ds[k] >= 0) {
            int b = ds[k] >> 7;
            int pos = atomicAdd(&hcur[b], 1);
            lrec[pos] = ((unsigned)ss[k] << 7) | (unsigned)(ds[k] & 127);
        }
    }
    __syncthreads();

    // publish: one global atomic per non-empty (block,bucket) run, then copy
    for (int k = tid; k < nbuk; k += 256) {
        int len = hcnt[k];
        if (len == 0) continue;
        int gb = atomicAdd(&cur[k], len);
        int lo = hofs[k];
        size_t rbase = (size_t)k * BCAP;
        for (int j = 0; j < len; ++j) {
            int p = gb + j;
            if (p < BCAP) ebuf[rbase + p] = lrec[lo + j];
        }
    }
}

// ---------------- CSR build, stage 2: one block per bucket ----------------
// Region is already bucket-contiguous: two coalesced passes (histogram,
// scatter; 2nd pass L2-hot). rp2[node] = {beg, deg} points into the bucket's
// FIXED col region -- no global prefix scan anywhere. Also converts this
// bucket's x rows to pre-scaled f16 (absorbs cvtpack).

__global__ void build_kernel(const unsigned* __restrict__ ebuf, const int* __restrict__ cur,
                             int2* __restrict__ rp2, int* __restrict__ col,
                             float* __restrict__ dinv, const float* __restrict__ x,
                             unsigned short* __restrict__ xb, int N) {
    __shared__ int deg[BUK];
    __shared__ int cursor[BUK];
    __shared__ float dl[BUK];
    __shared__ int shs[256];
    int b = blockIdx.x;
    int tid = threadIdx.x;
    int cnt = cur[b];
    if (cnt > BCAP) cnt = BCAP;
    if (tid < BUK) deg[tid] = 0;
    __syncthreads();

    int base = b * BCAP;
    for (int j = tid; j < cnt; j += 256) {
        atomicAdd(&deg[ebuf[(size_t)base + j] & (BUK - 1)], 1);
    }
    __syncthreads();

    int dv = (tid < BUK) ? deg[tid] : 0;
    shs[tid] = dv;
    __syncthreads();
    int val = dv;
    for (int off = 1; off < BUK; off <<= 1) {
        int add = 0;
        if (tid >= off && tid < BUK) add = shs[tid - off];
        __syncthreads();
        val += add;
        shs[tid] = val;
        __syncthreads();
    }
    int excl = val - dv;
    int nodeBase = b * BUK;
    if (tid < BUK) {
        int node = nodeBase + tid;
        float df = rsqrtf((float)dv + 1.0f);
        if (node < N) {
            rp2[node] = make_int2(base + excl, dv);
            dinv[node] = df;
        }
        dl[tid] = df;
        cursor[tid] = base + excl;
    }
    __syncthreads();

    for (int j = tid; j < cnt; j += 256) {
        unsigned rec = ebuf[(size_t)base + j];
        int pos = atomicAdd(&cursor[rec & (BUK - 1)], 1);
        col[pos] = (int)(rec >> 7);
    }

    // fused x -> f16 convert: xb[row] = dinv[row] * x[row]
    for (int g = tid; g < BUK * 16; g += 256) {
        int rr = g >> 4;
        int node2 = nodeBase + rr;
        if (node2 < N) {
            float dn = dl[rr];
            float4 vv = ((const float4*)x)[(size_t)node2 * 16 + (g & 15)];
            ushort4 o;
            o.x = f16r(vv.x * dn); o.y = f16r(vv.y * dn);
            o.z = f16r(vv.z * dn); o.w = f16r(vv.w * dn);
            ((ushort4*)xb)[(size_t)node2 * 16 + (g & 15)] = o;
        }
    }
}

// ---------------- fused aggregate + GEMM ----------------
// One block = one 16-node MFMA tile = 4 waves, 16 lanes per node
// (4 node-groups x 2 edge-slots x 8 channel-octs). Per 16-edge batch all 8
// gather loads are issued into a statically-indexed register array before
// any accumulate (sched_barrier pins the boundary); next batch's col/idx
// prefetched under the gathers. LDS row stride 72 shorts: 16B-aligned.

__launch_bounds__(256, 8)
__global__ void fused_relu_kernel(const unsigned short* __restrict__ h,
                                  const int2* __restrict__ rp2,
                                  const int* __restrict__ col,
                                  const float* __restrict__ dinv,
                                  const unsigned short* __restrict__ wp,
                                  const float* __restrict__ bias,
                                  unsigned short* __restrict__ out,
                                  int n, int zrow) {
    __shared__ unsigned short tile[16][72];
    if (blockIdx.x == 0 && threadIdx.x < 8) {
        *(uint4*)(out + (size_t)zrow * 64 + threadIdx.x * 8) = make_uint4(0, 0, 0, 0);
    }
    int tid = threadIdx.x;
    int w = tid >> 6;                    // wave id = t-tile id
    int lane = tid & 63;
    int g = lane >> 4;                   // node group 0..3
    int li = lane & 15;
    int sub = li >> 3;                   // edge slot 0/1
    unsigned choff = (li & 7) * 16u;     // byte offset of channel-oct in 128B row
    int nodeBase = blockIdx.x * 16;
    int row = w * 4 + g;
    int node = nodeBase + row;

    int beg = 0, deg = -1;
    float di = 0.f;
    if (node < n) {
        int2 bd = rp2[node];
        beg = bd.x;
        deg = bd.y;
        di = dinv[node];
    }
    int total = deg + 1;                 // + self edge (0 for invalid node)
    int nb = (total + 15) >> 4;          // 16-edge batches for this node
    nb = max(nb, __shfl_xor(nb, 16));    // wave-uniform max over the 4 groups
    nb = max(nb, __shfl_xor(nb, 32));

    half2v a0 = (half2v)0, a1 = (half2v)0, a2 = (half2v)0, a3 = (half2v)0;
    half2v c0 = (half2v)0, c1 = (half2v)0, c2 = (half2v)0, c3 = (half2v)0;

    // batch-0 idx
    int idx;
    {
        int e0 = li;
        idx = zrow;
        if (e0 < deg) idx = col[beg + e0];
        else if (e0 == deg) idx = node;
    }
    for (int b = 0; b < nb; ++b) {
        // prefetch next batch's idx under this batch's gathers
        int nidx = zrow;
        if (b + 1 < nb) {
            int e0 = ((b + 1) << 4) + li;
            if (e0 < deg) nidx = col[beg + e0];
            else if (e0 == deg) nidx = node;
        }
        uint4 u[8];
#pragma unroll
        for (int it = 0; it < 8; ++it) {
            int s = __shfl(idx, (g << 4) + it * 2 + sub);
            u[it] = *(const uint4*)((const char*)h + (((unsigned)s << 7) + choff));
        }
        __builtin_amdgcn_sched_barrier(0);   // all 8 gathers issued before consumes
#pragma unroll
        for (int it = 0; it < 8; ++it) {
            if (it & 1) { c0 += h2(u[it].x); c1 += h2(u[it].y); c2 += h2(u[it].z); c3 += h2(u[it].w); }
            else        { a0 += h2(u[it].x); a1 += h2(u[it].y); a2 += h2(u[it].z); a3 += h2(u[it].w); }
        }
        idx = nidx;
    }
    a0 += c0; a1 += c1; a2 += c2; a3 += c3;
    // reduce the 2 edge slots (lane bit 3)
    a0 += __builtin_bit_cast(half2v, __shfl_xor(__builtin_bit_cast(int, a0), 8));
    a1 += __builtin_bit_cast(half2v, __shfl_xor(__builtin_bit_cast(int, a1), 8));
    a2 += __builtin_bit_cast(half2v, __shfl_xor(__builtin_bit_cast(int, a2), 8));
    a3 += __builtin_bit_cast(half2v, __shfl_xor(__builtin_bit_cast(int, a3), 8));

    if (sub == 0) {
        half2v dih = __builtin_bit_cast(half2v, __builtin_amdgcn_cvt_pkrtz(di, di));
        a0 *= dih; a1 *= dih; a2 *= dih; a3 *= dih;   // v_pk_mul_f16
        uint4 o;
        o.x = __builtin_bit_cast(unsigned, a0);
        o.y = __builtin_bit_cast(unsigned, a1);
        o.z = __builtin_bit_cast(unsigned, a2);
        o.w = __builtin_bit_cast(unsigned, a3);
        *(uint4*)((char*)&tile[row][0] + choff) = o;
    }
    __syncthreads();

    // GEMM phase: wave w computes output cols [w*16, w*16+16).
    int q = lane >> 4, c = lane & 15;
    half8 bf0 = *(const half8*)(wp + w * 1024 + lane * 8);
    half8 bf1 = *(const half8*)(wp + w * 1024 + 512 + lane * 8);
    float bs = bias[w * 16 + c];
    half8 fa0 = *(const half8*)&tile[c][q * 8];
    half8 fa1 = *(const half8*)&tile[c][32 + q * 8];
    f32x4 z = {0.f, 0.f, 0.f, 0.f};
    z = __builtin_amdgcn_mfma_f32_16x16x32_f16(fa0, bf0, z, 0, 0, 0);
    z = __builtin_amdgcn_mfma_f32_16x16x32_f16(fa1, bf1, z, 0, 0, 0);
#pragma unroll
    for (int r = 0; r < 4; ++r) {
        int nodeW = nodeBase + q * 4 + r;
        if (nodeW < n) {
            float dn = dinv[nodeW];
            out[(size_t)nodeW * 64 + w * 16 + c] = f16r(fmaxf(z[r] + bs, 0.f) * dn);
        }
    }
}

// Final layer: same fused agg phase; wave 0 then runs all 3 t-tiles of
// A @ W2 + b2 and the log-softmax epilogue (40 cols).

__launch_bounds__(256, 8)
__global__ void fused_lsm_kernel(const unsigned short* __restrict__ h,
                                 const int2* __restrict__ rp2,
                                 const int* __restrict__ col,
                                 const float* __restrict__ dinv,
                                 const unsigned short* __restrict__ wp,
                                 const float* __restrict__ bias,
                                 float* __restrict__ out,
                                 int n, int zrow) {
    __shared__ unsigned short tile[16][72];
    int tid = threadIdx.x;
    int w = tid >> 6;
    int lane = tid & 63;
    int g = lane >> 4;
    int li = lane & 15;
    int sub = li >> 3;
    unsigned choff = (li & 7) * 16u;
    int nodeBase = blockIdx.x * 16;
    int row = w * 4 + g;
    int node = nodeBase + row;

    int beg = 0, deg = -1;
    float di = 0.f;
    if (node < n) {
        int2 bd = rp2[node];
        beg = bd.x;
        deg = bd.y;
        di = dinv[node];
    }
    int total = deg + 1;
    int nb = (total + 15) >> 4;
    nb = max(nb, __shfl_xor(nb, 16));
    nb = max(nb, __shfl_xor(nb, 32));

    half2v a0 = (half2v)0, a1 = (half2v)0, a2 = (half2v)0, a3 = (half2v)0;
    half2v c0a = (half2v)0, c1a = (half2v)0, c2a = (half2v)0, c3a = (half2v)0;

    int idx;
    {
        int e0 = li;
        idx = zrow;
        if (e0 < deg) idx = col[beg + e0];
        else if (e0 == deg) idx = node;
    }
    for (int b = 0; b < nb; ++b) {
        int nidx = zrow;
        if (b + 1 < nb) {
            int e0 = ((b + 1) << 4) + li;
            if (e0 < deg) nidx = col[beg + e0];
            else if (e0 == deg) nidx = node;
        }
        uint4 u[8];
#pragma unroll
        for (int it = 0; it < 8; ++it) {
            int s = __shfl(idx, (g << 4) + it * 2 + sub);
            u[it] = *(const uint4*)((const char*)h + (((unsigned)s << 7) + choff));
        }
        __builtin_amdgcn_sched_barrier(0);
#pragma unroll
        for (int it = 0; it < 8; ++it) {
            if (it & 1) { c0a += h2(u[it].x); c1a += h2(u[it].y); c2a += h2(u[it].z); c3a += h2(u[it].w); }
            else        { a0 += h2(u[it].x);  a1 += h2(u[it].y);  a2 += h2(u[it].z);  a3 += h2(u[it].w); }
        }
        idx = nidx;
    }
    a0 += c0a; a1 += c1a; a2 += c2a; a3 += c3a;
    a0 += __builtin_bit_cast(half2v, __shfl_xor(__builtin_bit_cast(int, a0), 8));
    a1 += __builtin_bit_cast(half2v, __shfl_xor(__builtin_bit_cast(int, a1), 8));
    a2 += __builtin_bit_cast(half2v, __shfl_xor(__builtin_bit_cast(int, a2), 8));
    a3 += __builtin_bit_cast(half2v, __shfl_xor(__builtin_bit_cast(int, a3), 8));

    if (sub == 0) {
        half2v dih = __builtin_bit_cast(half2v, __builtin_amdgcn_cvt_pkrtz(di, di));
        a0 *= dih; a1 *= dih; a2 *= dih; a3 *= dih;
        uint4 o;
        o.x = __builtin_bit_cast(unsigned, a0);
        o.y = __builtin_bit_cast(unsigned, a1);
        o.z = __builtin_bit_cast(unsigned, a2);
        o.w = __builtin_bit_cast(unsigned, a3);
        *(uint4*)((char*)&tile[row][0] + choff) = o;
    }
    __syncthreads();
    if (w != 0) return;

    int q = lane >> 4, c = lane & 15;
    bool v2ok = (c < 8);   // col 32+c < 40

    half8 bfrag[3][2];
#pragma unroll
    for (int t = 0; t < 3; ++t)
#pragma unroll
        for (int hh = 0; hh < 2; ++hh)
            bfrag[t][hh] = *(const half8*)(wp + t * 1024 + hh * 512 + lane * 8);
    float bs[3];
    bs[0] = bias[c];
    bs[1] = bias[16 + c];
    bs[2] = v2ok ? bias[32 + c] : 0.f;

    half8 fa0 = *(const half8*)&tile[c][q * 8];
    half8 fa1 = *(const half8*)&tile[c][32 + q * 8];

    f32x4 acc[3];
#pragma unroll
    for (int t = 0; t < 3; ++t) {
        f32x4 z = {0.f, 0.f, 0.f, 0.f};
        z = __builtin_amdgcn_mfma_f32_16x16x32_f16(fa0, bfrag[t][0], z, 0, 0, 0);
        z = __builtin_amdgcn_mfma_f32_16x16x32_f16(fa1, bfrag[t][1], z, 0, 0, 0);
        acc[t] = z;
    }

#pragma unroll
    for (int r = 0; r < 4; ++r) {
        int nodeW = nodeBase + q * 4 + r;
        if (nodeW < n) {
            float v0 = acc[0][r] + bs[0];
            float v1 = acc[1][r] + bs[1];
            float v2 = v2ok ? (acc[2][r] + bs[2]) : -INFINITY;
            float m = fmaxf(fmaxf(v0, v1), v2);
#pragma unroll
            for (int off = 1; off <= 8; off <<= 1) m = fmaxf(m, __shfl_xor(m, off));
            float s = expf(v0 - m) + expf(v1 - m) + (v2ok ? expf(v2 - m) : 0.f);
#pragma unroll
            for (int off = 1; off <= 8; off <<= 1) s += __shfl_xor(s, off);
            float ls = m + logf(s);
            float* orow = out + (size_t)nodeW * 40;
            orow[c] = v0 - ls;
            orow[16 + c] = v1 - ls;
            if (v2ok) orow[32 + c] = v2 - ls;
        }
    }
}

// ---------------- launch ----------------

extern "C" void kernel_launch(void* const* d_in, const int* in_sizes, int n_in,
                              void* d_out, int out_size, void* d_ws, size_t ws_size,
                              hipStream_t stream) {
    const float* x  = (const float*)d_in[0];
    const int* ei   = (const int*)d_in[1];
    const float* W1 = (const float*)d_in[2];
    const float* b1 = (const float*)d_in[3];
    const float* Wh = (const float*)d_in[4];
    const float* bh = (const float*)d_in[5];
    const float* W2 = (const float*)d_in[6];
    const float* b2 = (const float*)d_in[7];
    float* out = (float*)d_out;

    const int N = in_sizes[0] / 64;
    const int E = in_sizes[1] / 2;
    const int nblk = (E + 256 * EPT - 1) / (256 * EPT);  // scat1 blocks (391)
    const int nbuk = (N + BUK - 1) / BUK;                // 128-node buckets (782)
    const int nTiles = (N + 15) / 16;
    const int Npad = nTiles * 16;                        // zero-row index

    const int* srcp = ei;
    const int* dstp = ei + E;

    size_t off = 0;
    auto alloc = [&](size_t bytes) {
        size_t o = off;
        off = (off + bytes + 255) & ~(size_t)255;
        return o;
    };
    char* ws = (char*)d_ws;
    int*      cur     = (int*)(ws + alloc((size_t)nbuk * 4));
    int2*     rp2     = (int2*)(ws + alloc((size_t)N * 8));
    float*    dinv    = (float*)(ws + alloc((size_t)N * 4));
    int*      col     = (int*)(ws + alloc((size_t)nbuk * BCAP * 4));
    unsigned* ebuf    = (unsigned*)(ws + alloc((size_t)nbuk * BCAP * 4));
    unsigned short* wp1  = (unsigned short*)(ws + alloc(4096 * 2));
    unsigned short* wph  = (unsigned short*)(ws + alloc(4096 * 2));
    unsigned short* wp2  = (unsigned short*)(ws + alloc(3072 * 2));
    unsigned short* xb   = (unsigned short*)(ws + alloc((size_t)(Npad + 1) * 64 * 2));
    unsigned short* gA   = (unsigned short*)(ws + alloc((size_t)(Npad + 1) * 64 * 2));
    unsigned short* gB   = (unsigned short*)(ws + alloc((size_t)(Npad + 1) * 64 * 2));
    (void)ws_size;

    hipMemsetAsync(cur, 0, (size_t)nbuk * 4, stream);

    scat1_pack_kernel<<<nblk + 16, 256, 0, stream>>>(srcp, dstp, cur, ebuf,
                                                     W1, Wh, W2, wp1, wph, wp2,
                                                     xb, Npad, E, nblk, nbuk);
    build_kernel<<<nbuk, 256, 0, stream>>>(ebuf, cur, rp2, col, dinv, x, xb, N);

    // layer 1: xb -> gA     (agg + GEMM fused)
    fused_relu_kernel<<<nTiles, 256, 0, stream>>>(xb, rp2, col, dinv, wp1, b1, gA, N, Npad);
    // layer 2: gA -> gB
    fused_relu_kernel<<<nTiles, 256, 0, stream>>>(gA, rp2, col, dinv, wph, bh, gB, N, Npad);
    // layer 3: gB -> out (log-softmax, fp32)
    fused_lsm_kernel<<<nTiles, 256, 0, stream>>>(gB, rp2, col, dinv, wp2, b2, out, N, Npad);
}